// Round 5
// baseline (180.929 us; speedup 1.0000x reference)
//
#include <hip/hip_runtime.h>
#include <math.h>

// Problem constants: B=32, C=D=64, H=W=32
#define NPTS 32768      // B*H*W
#define KCB  1024
#define DIM  64
#define HW   1024
#define CHW  65536
#define PT   128        // points per block (k_dist)
#define RWIN 2          // OT band radius (validated R3/R4: absmax 0.0)

__device__ __forceinline__ float block_sum(float v, float* scratch) {
  #pragma unroll
  for (int o = 32; o > 0; o >>= 1) v += __shfl_down(v, o, 64);
  int wid  = threadIdx.x >> 6;
  int lane = threadIdx.x & 63;
  __syncthreads();
  if (lane == 0) scratch[wid] = v;
  __syncthreads();
  float s = 0.f;
  int nw = blockDim.x >> 6;
  for (int w = 0; w < nw; ++w) s += scratch[w];
  return s;
}

// K0: blocks 0..255: per-point ||x||^2 (coalesced, bit-exact c-ordered fmaf chain);
//     blocks 256..263: codebook row norms (same f4 chain as prior rounds).
__global__ __launch_bounds__(128) void k_pre(const float* __restrict__ x,
                                             const float* __restrict__ cb,
                                             float* __restrict__ sumx_g,
                                             float* __restrict__ cnorm) {
  int blk = blockIdx.x, tid = threadIdx.x;
  if (blk < 256) {
    int n = blk * 128 + tid;
    int b = n >> 10, hw = n & 1023;
    const float* xp = x + b * CHW + hw;
    float s = 0.f;
    #pragma unroll
    for (int c = 0; c < DIM; ++c) { float v = xp[c * HW]; s = fmaf(v, v, s); }
    sumx_g[n] = s;
  } else {
    int k = (blk - 256) * 128 + tid;
    const float4* c4 = (const float4*)(cb + k * DIM);
    float s = 0.f;
    #pragma unroll
    for (int d = 0; d < DIM/4; ++d) {
      float4 v = c4[d];
      s = fmaf(v.x, v.x, s); s = fmaf(v.y, v.y, s);
      s = fmaf(v.z, v.z, s); s = fmaf(v.w, v.w, s);
    }
    cnorm[k] = s;
  }
}

// K1: distance GEMM, 512 blocks (256 pt-tiles x 2 code-halves), 2 blocks/CU.
// Thread tile 8 pts x 16 codes (0.75 B/MAC). lc holds 32-dim x 256-code chunks
// (identity col layout, strided-quad read assignment -> all LDS 2-way = free).
// Winner via packed-u64 global atomicMin (ws poison 0xAA.. > any real packed value).
__global__ __launch_bounds__(256, 2) void k_dist(const float* __restrict__ x,
                                                 const float* __restrict__ cb,
                                                 const float* __restrict__ cnorm,
                                                 const float* __restrict__ sumx_g,
                                                 unsigned long long* __restrict__ pmin) {
  __shared__ __align__(16) float lp[DIM][132];   // points, split lo/hi cols, pad->2-way
  __shared__ __align__(16) float lc[32][256];    // code chunk, dim-major, identity cols
  int tid = threadIdx.x;
  int t   = blockIdx.x;
  int kb  = blockIdx.y * 512;
  int n0  = t * PT;
  int b   = n0 >> 10;
  int hw0 = n0 & 1023;

  // stage points: f4 of pts 4*p4..4*p4+3 (dim crow-major) -> col (p4&1)*64+(p4>>1)*4
  {
    const float* xb = x + b * CHW + hw0;
    int crow = tid >> 5, p4 = tid & 31;
    int col0 = (p4 & 1) * 64 + (p4 >> 1) * 4;
    #pragma unroll
    for (int i = 0; i < 8; ++i) {
      int c = i * 8 + crow;
      *(float4*)&lp[c][col0] = *(const float4*)(xb + c * HW + p4 * 4);
    }
  }

  int tx = tid & 15, ty = tid >> 4;
  float4 sx0 = *(const float4*)(sumx_g + n0 + ty * 8);
  float4 sx1 = *(const float4*)(sumx_g + n0 + ty * 8 + 4);
  float sx[8] = {sx0.x, sx0.y, sx0.z, sx0.w, sx1.x, sx1.y, sx1.z, sx1.w};

  float best[8];
  int   bidx[8];
  #pragma unroll
  for (int pp = 0; pp < 8; ++pp) { best[pp] = 3.4e38f; bidx[pp] = 0; }

  for (int ct = 0; ct < 2; ++ct) {
    int k0 = kb + ct * 256;
    float acc[8][16];
    #pragma unroll
    for (int pp = 0; pp < 8; ++pp)
      #pragma unroll
      for (int cc = 0; cc < 16; ++cc) acc[pp][cc] = 0.f;

    for (int dh = 0; dh < 2; ++dh) {
      __syncthreads();   // protect lc from previous phase readers
      // stage: thread stages code k0+tid, dims dh*32..+31, into column tid (bank=lane: 2-way free)
      {
        const float4* row = (const float4*)(cb + (k0 + tid) * DIM) + dh * 8;
        #pragma unroll
        for (int i = 0; i < 8; ++i) {
          float4 v = row[i];
          int d = i * 4;
          lc[d + 0][tid] = v.x;
          lc[d + 1][tid] = v.y;
          lc[d + 2][tid] = v.z;
          lc[d + 3][tid] = v.w;
        }
      }
      __syncthreads();

      int dbase = dh * 32;
      #pragma unroll 4
      for (int dd = 0; dd < 32; ++dd) {
        int d = dbase + dd;
        float4 a0 = *(const float4*)&lp[d][4 * ty];        // pts ty*8..+3
        float4 a1 = *(const float4*)&lp[d][64 + 4 * ty];   // pts ty*8+4..+7
        float4 b0 = *(const float4*)&lc[dd][4 * tx];          // codes k0+4tx..+3
        float4 b1 = *(const float4*)&lc[dd][64 + 4 * tx];     // k0+64+4tx..
        float4 b2 = *(const float4*)&lc[dd][128 + 4 * tx];    // k0+128+4tx..
        float4 b3 = *(const float4*)&lc[dd][192 + 4 * tx];    // k0+192+4tx..
        float av[8]  = {a0.x, a0.y, a0.z, a0.w, a1.x, a1.y, a1.z, a1.w};
        float bv[16] = {b0.x, b0.y, b0.z, b0.w, b1.x, b1.y, b1.z, b1.w,
                        b2.x, b2.y, b2.z, b2.w, b3.x, b3.y, b3.z, b3.w};
        #pragma unroll
        for (int pp = 0; pp < 8; ++pp) {
          float a = av[pp];
          #pragma unroll
          for (int cc = 0; cc < 16; ++cc)
            acc[pp][cc] = fmaf(a, bv[cc], acc[pp][cc]);   // d-ordered chain == np
        }
      }
    }

    // fold this 256-code chunk (k = k0 + 64*q + 4*tx + e, ascending -> first-min)
    float cn[16];
    #pragma unroll
    for (int q = 0; q < 4; ++q) {
      float4 c4 = *(const float4*)(cnorm + k0 + 64 * q + 4 * tx);
      cn[q*4+0] = c4.x; cn[q*4+1] = c4.y; cn[q*4+2] = c4.z; cn[q*4+3] = c4.w;
    }
    #pragma unroll
    for (int pp = 0; pp < 8; ++pp) {
      #pragma unroll
      for (int cc = 0; cc < 16; ++cc) {
        // reference fp32 rounding: (||x||^2 + ||c||^2) - 2*x.c
        float dist = (sx[pp] + cn[cc]) - 2.0f * acc[pp][cc];
        int   k    = k0 + 64 * (cc >> 2) + 4 * tx + (cc & 3);
        if (dist < best[pp]) { best[pp] = dist; bidx[pp] = k; }
      }
    }
  }

  // cross-tx argmin (16-lane groups), then cross-block via u64 atomicMin.
  // dist>0 always => packed < 0x8000.. < 0xAAAA.. ws poison: no init needed.
  #pragma unroll
  for (int pp = 0; pp < 8; ++pp) {
    unsigned long long pk =
        ((unsigned long long)__float_as_uint(best[pp]) << 32) | (unsigned)bidx[pp];
    #pragma unroll
    for (int m = 1; m < 16; m <<= 1) {
      unsigned long long o = __shfl_xor(pk, m, 64);
      pk = (o < pk) ? o : pk;
    }
    if (tx == 0) atomicMin(&pmin[n0 + ty * 8 + pp], pk);
  }
}

// K2: gather + straight-through write + commit-mse partial (adds 1.25*mse/N into out loss slot)
__global__ __launch_bounds__(256) void k_fin(const float* __restrict__ x,
                                             const float* __restrict__ cb,
                                             const unsigned long long* __restrict__ pmin,
                                             float* __restrict__ out) {
  __shared__ float scratch[4];
  int n = blockIdx.x * 256 + threadIdx.x;
  int bidx = (int)(pmin[n] & 0xffffffffull);
  int b = n >> 10, hw = n & 1023;
  const float* xp = x + b * CHW + hw;
  float* op = out + b * CHW + hw;
  const float4* q4 = (const float4*)(cb + bidx * DIM);
  float se = 0.f;
  #pragma unroll
  for (int d = 0; d < DIM/4; ++d) {
    float4 q = q4[d];
    float qq[4] = {q.x, q.y, q.z, q.w};
    #pragma unroll
    for (int j = 0; j < 4; ++j) {
      int c = 4 * d + j;
      float xv = xp[c * HW];
      float diff = qq[j] - xv;       // nq - x
      se += diff * diff;             // (clean_q - flat)^2 == commit mse
      op[c * HW] = xv + diff;        // x + stop_grad(nq - x), ref rounding
    }
  }
  float tot = block_sum(se, scratch);
  if (threadIdx.x == 0)
    atomicAdd(&out[2097152], tot * 1.25f * (1.0f / 2097152.0f));
}

// K3: hist from pmin + prep + banded OT dual ascent + scalars.
// 256 threads x 4 elems: 4 waves (cheap barriers), 4x ILP on exp chains.
__global__ __launch_bounds__(256) void k_ot(const unsigned long long* __restrict__ pmin,
                                            float* __restrict__ out) {
  __shared__ int s_hist[KCB];
  __shared__ __align__(16) float s_lt[KCB + 8], s_src[KCB + 8],
                                 s_phi[KCB + 8], s_lse[KCB + 8];
  __shared__ float scratch[4];
  int tid = threadIdx.x;
  int i0  = tid * 4;
  int sl0 = i0 + 4;          // arrays padded by 4 each side; valid sl in [4, 1028)

  #pragma unroll
  for (int q = 0; q < 4; ++q) s_hist[tid + 256 * q] = 0;
  __syncthreads();
  for (int q = 0; q < 128; ++q) {
    unsigned long long pk = pmin[tid + 256 * q];
    atomicAdd(&s_hist[(int)(pk & 0xffffffffull)], 1);
  }
  __syncthreads();

  // Gaussian target + norm_prob(x2); src = norm_prob(norm_prob(hard_hist)); entropy
  float tj[4], hj[4];
  #pragma unroll
  for (int j = 0; j < 4; ++j) {
    float fi = (float)(i0 + j);
    float zz = (fi - 511.5f) / (1024.0f / 6.0f);
    tj[j] = expf(-0.5f * zz * zz);
    hj[j] = (float)s_hist[i0 + j] * (1.0f / 32768.0f);
  }
  float St = block_sum(tj[0] + tj[1] + tj[2] + tj[3], scratch);
  float tgt[4], ltw[4];
  float l2 = 0.f;
  #pragma unroll
  for (int j = 0; j < 4; ++j) { tgt[j] = fmaxf(tj[j] / fmaxf(St, 1e-12f), 1e-12f); l2 += tgt[j]; }
  float St2 = block_sum(l2, scratch);
  #pragma unroll
  for (int j = 0; j < 4; ++j) { tgt[j] = tgt[j] / St2; ltw[j] = logf(fmaxf(tgt[j], 1e-12f)); }

  float m1[4], srcw[4];
  float l3 = 0.f;
  #pragma unroll
  for (int j = 0; j < 4; ++j) { m1[j] = fmaxf(hj[j], 1e-12f); l3 += m1[j]; }
  float S1 = block_sum(l3, scratch);
  float l4 = 0.f;
  #pragma unroll
  for (int j = 0; j < 4; ++j) { srcw[j] = fmaxf(m1[j] / S1, 1e-12f); l4 += srcw[j]; }
  float S2 = block_sum(l4, scratch);
  float l5 = 0.f;
  #pragma unroll
  for (int j = 0; j < 4; ++j) { srcw[j] = srcw[j] / S2; l5 += hj[j] * logf(hj[j] + 1e-10f); }
  float ent = block_sum(l5, scratch);

  *(float4*)&s_lt[sl0]  = *(float4*)ltw;
  *(float4*)&s_src[sl0] = *(float4*)srcw;
  *(float4*)&s_phi[sl0] = make_float4(0.f, 0.f, 0.f, 0.f);
  *(float4*)&s_lse[sl0] = make_float4(0.f, 0.f, 0.f, 0.f);
  if (tid == 0) {    // pads: inert (exp args flush below eps of row max — validated R3/R4)
    #pragma unroll
    for (int p = 0; p < 4; ++p) {
      s_lt[p] = -100.f; s_src[p] = 0.f; s_phi[p] = 0.f; s_lse[p] = 0.f;
      s_lt[KCB+4+p] = -100.f; s_src[KCB+4+p] = 0.f; s_phi[KCB+4+p] = 0.f; s_lse[KCB+4+p] = 0.f;
    }
  }
  __syncthreads();

  // static src window [i0-2 .. i0+9] -> sl [sl0-2, sl0+9] in [4t+2, 4t+12)
  float ws[12];
  #pragma unroll
  for (int m = 0; m < 3; ++m) *(float4*)&ws[m*4] = *(float4*)&s_src[i0 + m*4];

  float phi[4] = {0.f, 0.f, 0.f, 0.f};
  float lse[4];
  for (int it = 0; it <= 10; ++it) {
    // Phase A: lse_i = logsumexp over band of [lt_j + 20*(phi_j - |i-j|)]
    float wl[12], wp[12];
    #pragma unroll
    for (int m = 0; m < 3; ++m) {
      *(float4*)&wl[m*4] = *(float4*)&s_lt[i0 + m*4];
      *(float4*)&wp[m*4] = *(float4*)&s_phi[i0 + m*4];
    }
    #pragma unroll
    for (int j = 0; j < 4; ++j) {
      float mx = -3.0e38f;
      float vv[5];
      #pragma unroll
      for (int q = 0; q < 5; ++q) {
        int m = j + q + 2;   // sl index offset: (i0+j-2+q) + 4 - i0
        float a = wl[m] + (wp[m] - fabsf((float)(q - 2))) * 20.0f;
        vv[q] = a;
        mx = fmaxf(mx, a);
      }
      float ssum = 0.f;
      #pragma unroll
      for (int q = 0; q < 5; ++q) ssum += expf(vv[q] - mx);
      lse[j] = mx + logf(ssum);
    }
    *(float4*)&s_lse[sl0] = *(float4*)lse;
    __syncthreads();
    if (it == 10) break;

    // Phase B: cs_j = sum_r src_r * exp(lt_j + 20*phi_j - 20|j-r| - lse_r)
    float we[12];
    #pragma unroll
    for (int m = 0; m < 3; ++m) *(float4*)&we[m*4] = *(float4*)&s_lse[i0 + m*4];
    #pragma unroll
    for (int j = 0; j < 4; ++j) {
      float basej = ltw[j] + phi[j] * 20.0f;
      float cs = 0.f;
      #pragma unroll
      for (int q = 0; q < 5; ++q) {
        int m = j + q + 2;
        float a = basej - fabsf((float)(q - 2)) * 20.0f;
        cs += ws[m] * expf(a - we[m]);
      }
      phi[j] += 0.5f * (tgt[j] - cs);
    }
    *(float4*)&s_phi[sl0] = *(float4*)phi;
    __syncthreads();
  }

  float lo = 0.f;
  #pragma unroll
  for (int j = 0; j < 4; ++j) lo += srcw[j] * (-0.05f * lse[j]) + tgt[j] * phi[j];
  float ot = block_sum(lo, scratch);

  if (tid == 0) {
    atomicAdd(&out[2097152], ot);     // k_fin already added 1.25*mse
    out[2097153] = expf(-ent);        // perplexity
  }
}

extern "C" void kernel_launch(void* const* d_in, const int* in_sizes, int n_in,
                              void* d_out, int out_size, void* d_ws, size_t ws_size,
                              hipStream_t stream) {
  const float* x  = (const float*)d_in[0];   // [32,64,32,32]
  const float* cb = (const float*)d_in[1];   // [1024,64]
  float* out = (float*)d_out;                // quantized(2097152) | loss | perplexity

  float* sumx_g = (float*)d_ws;                                   // 128 KB
  float* cnorm  = (float*)((char*)d_ws + 131072);                 // 4 KB
  unsigned long long* pmin = (unsigned long long*)((char*)d_ws + 262144);  // 256 KB (poison-init OK)

  hipMemsetAsync(out + 2097152, 0, 8, stream);   // loss+perp accumulators
  k_pre<<<264, 128, 0, stream>>>(x, cb, sumx_g, cnorm);
  k_dist<<<dim3(NPTS / PT, 2), 256, 0, stream>>>(x, cb, cnorm, sumx_g, pmin);
  k_fin<<<NPTS / 256, 256, 0, stream>>>(x, cb, pmin, out);
  k_ot<<<1, 256, 0, stream>>>(pmin, out);
}

// Round 6
// 161.019 us; speedup vs baseline: 1.1236x; 1.1236x over previous
//
#include <hip/hip_runtime.h>
#include <math.h>

// Problem constants: B=32, C=D=64, H=W=32
#define NPTS 32768      // B*H*W
#define KCB  1024
#define DIM  64
#define HW   1024
#define CHW  65536
#define PT   128        // points per block (k_dist)
#define RWIN 2          // OT band radius (validated R3/R4/R5: absmax 0.0)

__device__ __forceinline__ float block_sum(float v, float* scratch) {
  #pragma unroll
  for (int o = 32; o > 0; o >>= 1) v += __shfl_down(v, o, 64);
  int wid  = threadIdx.x >> 6;
  int lane = threadIdx.x & 63;
  __syncthreads();
  if (lane == 0) scratch[wid] = v;
  __syncthreads();
  float s = 0.f;
  int nw = blockDim.x >> 6;
  for (int w = 0; w < nw; ++w) s += scratch[w];
  return s;
}

// K0: blocks 0..255: per-point ||x||^2 (coalesced, bit-exact c-ordered fmaf chain);
//     blocks 256..263: codebook row norms (same f4 chain as prior rounds).
__global__ __launch_bounds__(128) void k_pre(const float* __restrict__ x,
                                             const float* __restrict__ cb,
                                             float* __restrict__ sumx_g,
                                             float* __restrict__ cnorm) {
  int blk = blockIdx.x, tid = threadIdx.x;
  if (blk < 256) {
    int n = blk * 128 + tid;
    int b = n >> 10, hw = n & 1023;
    const float* xp = x + b * CHW + hw;
    float s = 0.f;
    #pragma unroll
    for (int c = 0; c < DIM; ++c) { float v = xp[c * HW]; s = fmaf(v, v, s); }
    sumx_g[n] = s;
  } else {
    int k = (blk - 256) * 128 + tid;
    const float4* c4 = (const float4*)(cb + k * DIM);
    float s = 0.f;
    #pragma unroll
    for (int d = 0; d < DIM/4; ++d) {
      float4 v = c4[d];
      s = fmaf(v.x, v.x, s); s = fmaf(v.y, v.y, s);
      s = fmaf(v.z, v.z, s); s = fmaf(v.w, v.w, s);
    }
    cnorm[k] = s;
  }
}

// K1: distance GEMM, 512 blocks (256 pt-tiles x 2 code-halves), 2 blocks/CU.
// Thread tile 8 pts x 16 codes (0.75 B/MAC). lc: 32-dim x 256-code chunks,
// identity col layout (stores bank=lane 2-way free; reads 16 distinct f4 addrs 2-way free).
// Winner via packed-u64 global atomicMin (ws poison 0xAA.. > any real packed value).
__global__ __launch_bounds__(256, 2) void k_dist(const float* __restrict__ x,
                                                 const float* __restrict__ cb,
                                                 const float* __restrict__ cnorm,
                                                 const float* __restrict__ sumx_g,
                                                 unsigned long long* __restrict__ pmin) {
  __shared__ __align__(16) float lp[DIM][132];   // points, split lo/hi cols, pad->2-way
  __shared__ __align__(16) float lc[32][256];    // code chunk, dim-major, identity cols
  int tid = threadIdx.x;
  int t   = blockIdx.x;
  int kb  = blockIdx.y * 512;
  int n0  = t * PT;
  int b   = n0 >> 10;
  int hw0 = n0 & 1023;

  // stage points: f4 of pts 4*p4..4*p4+3 (dim crow-major) -> col (p4&1)*64+(p4>>1)*4
  {
    const float* xb = x + b * CHW + hw0;
    int crow = tid >> 5, p4 = tid & 31;
    int col0 = (p4 & 1) * 64 + (p4 >> 1) * 4;
    #pragma unroll
    for (int i = 0; i < 8; ++i) {
      int c = i * 8 + crow;
      *(float4*)&lp[c][col0] = *(const float4*)(xb + c * HW + p4 * 4);
    }
  }

  int tx = tid & 15, ty = tid >> 4;
  float4 sx0 = *(const float4*)(sumx_g + n0 + ty * 8);
  float4 sx1 = *(const float4*)(sumx_g + n0 + ty * 8 + 4);
  float sx[8] = {sx0.x, sx0.y, sx0.z, sx0.w, sx1.x, sx1.y, sx1.z, sx1.w};

  float best[8];
  int   bidx[8];
  #pragma unroll
  for (int pp = 0; pp < 8; ++pp) { best[pp] = 3.4e38f; bidx[pp] = 0; }

  for (int ct = 0; ct < 2; ++ct) {
    int k0 = kb + ct * 256;
    float acc[8][16];
    #pragma unroll
    for (int pp = 0; pp < 8; ++pp)
      #pragma unroll
      for (int cc = 0; cc < 16; ++cc) acc[pp][cc] = 0.f;

    for (int dh = 0; dh < 2; ++dh) {
      __syncthreads();   // protect lc from previous phase readers
      // stage: thread stages code k0+tid, dims dh*32..+31, into column tid
      {
        const float4* row = (const float4*)(cb + (k0 + tid) * DIM) + dh * 8;
        #pragma unroll
        for (int i = 0; i < 8; ++i) {
          float4 v = row[i];
          int d = i * 4;
          lc[d + 0][tid] = v.x;
          lc[d + 1][tid] = v.y;
          lc[d + 2][tid] = v.z;
          lc[d + 3][tid] = v.w;
        }
      }
      __syncthreads();

      int dbase = dh * 32;
      #pragma unroll 4
      for (int dd = 0; dd < 32; ++dd) {
        int d = dbase + dd;
        float4 a0 = *(const float4*)&lp[d][4 * ty];        // pts ty*8..+3
        float4 a1 = *(const float4*)&lp[d][64 + 4 * ty];   // pts ty*8+4..+7
        float4 b0 = *(const float4*)&lc[dd][4 * tx];          // codes k0+4tx..+3
        float4 b1 = *(const float4*)&lc[dd][64 + 4 * tx];     // k0+64+4tx..
        float4 b2 = *(const float4*)&lc[dd][128 + 4 * tx];    // k0+128+4tx..
        float4 b3 = *(const float4*)&lc[dd][192 + 4 * tx];    // k0+192+4tx..
        float av[8]  = {a0.x, a0.y, a0.z, a0.w, a1.x, a1.y, a1.z, a1.w};
        float bv[16] = {b0.x, b0.y, b0.z, b0.w, b1.x, b1.y, b1.z, b1.w,
                        b2.x, b2.y, b2.z, b2.w, b3.x, b3.y, b3.z, b3.w};
        #pragma unroll
        for (int pp = 0; pp < 8; ++pp) {
          float a = av[pp];
          #pragma unroll
          for (int cc = 0; cc < 16; ++cc)
            acc[pp][cc] = fmaf(a, bv[cc], acc[pp][cc]);   // d-ordered chain == np
        }
      }
    }

    // fold this 256-code chunk (k = k0 + 64*q + 4*tx + e, ascending -> first-min)
    float cn[16];
    #pragma unroll
    for (int q = 0; q < 4; ++q) {
      float4 c4 = *(const float4*)(cnorm + k0 + 64 * q + 4 * tx);
      cn[q*4+0] = c4.x; cn[q*4+1] = c4.y; cn[q*4+2] = c4.z; cn[q*4+3] = c4.w;
    }
    #pragma unroll
    for (int pp = 0; pp < 8; ++pp) {
      #pragma unroll
      for (int cc = 0; cc < 16; ++cc) {
        // reference fp32 rounding: (||x||^2 + ||c||^2) - 2*x.c
        float dist = (sx[pp] + cn[cc]) - 2.0f * acc[pp][cc];
        int   k    = k0 + 64 * (cc >> 2) + 4 * tx + (cc & 3);
        if (dist < best[pp]) { best[pp] = dist; bidx[pp] = k; }
      }
    }
  }

  // cross-tx argmin (16-lane groups), then cross-block via u64 atomicMin.
  #pragma unroll
  for (int pp = 0; pp < 8; ++pp) {
    unsigned long long pk =
        ((unsigned long long)__float_as_uint(best[pp]) << 32) | (unsigned)bidx[pp];
    #pragma unroll
    for (int m = 1; m < 16; m <<= 1) {
      unsigned long long o = __shfl_xor(pk, m, 64);
      pk = (o < pk) ? o : pk;
    }
    if (tx == 0) atomicMin(&pmin[n0 + ty * 8 + pp], pk);
  }
}

// K2: gather + straight-through write + commit-mse partial + hist count.
// Hist built here (32K spread global atomics over 128 blocks) — NOT in the
// single-block k_ot, where the serial load+LDS-atomic loop cost 78 us (R5 lesson).
__global__ __launch_bounds__(256) void k_fin(const float* __restrict__ x,
                                             const float* __restrict__ cb,
                                             const unsigned long long* __restrict__ pmin,
                                             int* __restrict__ hist,
                                             float* __restrict__ out) {
  __shared__ float scratch[4];
  int n = blockIdx.x * 256 + threadIdx.x;
  int bidx = (int)(pmin[n] & 0xffffffffull);
  atomicAdd(&hist[bidx], 1);
  int b = n >> 10, hw = n & 1023;
  const float* xp = x + b * CHW + hw;
  float* op = out + b * CHW + hw;
  const float4* q4 = (const float4*)(cb + bidx * DIM);
  float se = 0.f;
  #pragma unroll
  for (int d = 0; d < DIM/4; ++d) {
    float4 q = q4[d];
    float qq[4] = {q.x, q.y, q.z, q.w};
    #pragma unroll
    for (int j = 0; j < 4; ++j) {
      int c = 4 * d + j;
      float xv = xp[c * HW];
      float diff = qq[j] - xv;       // nq - x
      se += diff * diff;             // (clean_q - flat)^2 == commit mse
      op[c * HW] = xv + diff;        // x + stop_grad(nq - x), ref rounding
    }
  }
  float tot = block_sum(se, scratch);
  if (threadIdx.x == 0)
    atomicAdd(&out[2097152], tot * 1.25f * (1.0f / 2097152.0f));
}

// K3: prep + banded OT dual ascent + scalars. 256 threads x 4 elems.
// Reads hist[1024] directly (4 KB) — no per-point loop.
__global__ __launch_bounds__(256) void k_ot(const int* __restrict__ hist,
                                            float* __restrict__ out) {
  __shared__ __align__(16) float s_lt[KCB + 8], s_src[KCB + 8],
                                 s_phi[KCB + 8], s_lse[KCB + 8];
  __shared__ float scratch[4];
  int tid = threadIdx.x;
  int i0  = tid * 4;
  int sl0 = i0 + 4;          // arrays padded by 4 each side; valid sl in [4, 1028)

  // Gaussian target + norm_prob(x2); src = norm_prob(norm_prob(hard_hist)); entropy
  int4 hi4 = *(const int4*)(hist + i0);
  int  hi[4] = {hi4.x, hi4.y, hi4.z, hi4.w};
  float tj[4], hj[4];
  #pragma unroll
  for (int j = 0; j < 4; ++j) {
    float fi = (float)(i0 + j);
    float zz = (fi - 511.5f) / (1024.0f / 6.0f);
    tj[j] = expf(-0.5f * zz * zz);
    hj[j] = (float)hi[j] * (1.0f / 32768.0f);
  }
  float St = block_sum(tj[0] + tj[1] + tj[2] + tj[3], scratch);
  float tgt[4], ltw[4];
  float l2 = 0.f;
  #pragma unroll
  for (int j = 0; j < 4; ++j) { tgt[j] = fmaxf(tj[j] / fmaxf(St, 1e-12f), 1e-12f); l2 += tgt[j]; }
  float St2 = block_sum(l2, scratch);
  #pragma unroll
  for (int j = 0; j < 4; ++j) { tgt[j] = tgt[j] / St2; ltw[j] = logf(fmaxf(tgt[j], 1e-12f)); }

  float m1[4], srcw[4];
  float l3 = 0.f;
  #pragma unroll
  for (int j = 0; j < 4; ++j) { m1[j] = fmaxf(hj[j], 1e-12f); l3 += m1[j]; }
  float S1 = block_sum(l3, scratch);
  float l4 = 0.f;
  #pragma unroll
  for (int j = 0; j < 4; ++j) { srcw[j] = fmaxf(m1[j] / S1, 1e-12f); l4 += srcw[j]; }
  float S2 = block_sum(l4, scratch);
  float l5 = 0.f;
  #pragma unroll
  for (int j = 0; j < 4; ++j) { srcw[j] = srcw[j] / S2; l5 += hj[j] * logf(hj[j] + 1e-10f); }
  float ent = block_sum(l5, scratch);

  *(float4*)&s_lt[sl0]  = *(float4*)ltw;
  *(float4*)&s_src[sl0] = *(float4*)srcw;
  *(float4*)&s_phi[sl0] = make_float4(0.f, 0.f, 0.f, 0.f);
  *(float4*)&s_lse[sl0] = make_float4(0.f, 0.f, 0.f, 0.f);
  if (tid == 0) {    // pads: inert (exp args flush below eps of row max — validated R3/R4/R5)
    #pragma unroll
    for (int p = 0; p < 4; ++p) {
      s_lt[p] = -100.f; s_src[p] = 0.f; s_phi[p] = 0.f; s_lse[p] = 0.f;
      s_lt[KCB+4+p] = -100.f; s_src[KCB+4+p] = 0.f; s_phi[KCB+4+p] = 0.f; s_lse[KCB+4+p] = 0.f;
    }
  }
  __syncthreads();

  // static src window [i0-2 .. i0+9] -> sl [sl0-2, sl0+9]
  float ws[12];
  #pragma unroll
  for (int m = 0; m < 3; ++m) *(float4*)&ws[m*4] = *(float4*)&s_src[i0 + m*4];

  float phi[4] = {0.f, 0.f, 0.f, 0.f};
  float lse[4];
  for (int it = 0; it <= 10; ++it) {
    // Phase A: lse_i = logsumexp over band of [lt_j + 20*(phi_j - |i-j|)]
    float wl[12], wp[12];
    #pragma unroll
    for (int m = 0; m < 3; ++m) {
      *(float4*)&wl[m*4] = *(float4*)&s_lt[i0 + m*4];
      *(float4*)&wp[m*4] = *(float4*)&s_phi[i0 + m*4];
    }
    #pragma unroll
    for (int j = 0; j < 4; ++j) {
      float mx = -3.0e38f;
      float vv[5];
      #pragma unroll
      for (int q = 0; q < 5; ++q) {
        int m = j + q + 2;   // sl offset: (i0+j-2+q) + 4 - i0
        float a = wl[m] + (wp[m] - fabsf((float)(q - 2))) * 20.0f;
        vv[q] = a;
        mx = fmaxf(mx, a);
      }
      float ssum = 0.f;
      #pragma unroll
      for (int q = 0; q < 5; ++q) ssum += expf(vv[q] - mx);
      lse[j] = mx + logf(ssum);
    }
    *(float4*)&s_lse[sl0] = *(float4*)lse;
    __syncthreads();
    if (it == 10) break;

    // Phase B: cs_j = sum_r src_r * exp(lt_j + 20*phi_j - 20|j-r| - lse_r)
    float we[12];
    #pragma unroll
    for (int m = 0; m < 3; ++m) *(float4*)&we[m*4] = *(float4*)&s_lse[i0 + m*4];
    #pragma unroll
    for (int j = 0; j < 4; ++j) {
      float basej = ltw[j] + phi[j] * 20.0f;
      float cs = 0.f;
      #pragma unroll
      for (int q = 0; q < 5; ++q) {
        int m = j + q + 2;
        float a = basej - fabsf((float)(q - 2)) * 20.0f;
        cs += ws[m] * expf(a - we[m]);
      }
      phi[j] += 0.5f * (tgt[j] - cs);
    }
    *(float4*)&s_phi[sl0] = *(float4*)phi;
    __syncthreads();
  }

  float lo = 0.f;
  #pragma unroll
  for (int j = 0; j < 4; ++j) lo += srcw[j] * (-0.05f * lse[j]) + tgt[j] * phi[j];
  float ot = block_sum(lo, scratch);

  if (tid == 0) {
    atomicAdd(&out[2097152], ot);     // k_fin already added 1.25*mse
    out[2097153] = expf(-ent);        // perplexity
  }
}

extern "C" void kernel_launch(void* const* d_in, const int* in_sizes, int n_in,
                              void* d_out, int out_size, void* d_ws, size_t ws_size,
                              hipStream_t stream) {
  const float* x  = (const float*)d_in[0];   // [32,64,32,32]
  const float* cb = (const float*)d_in[1];   // [1024,64]
  float* out = (float*)d_out;                // quantized(2097152) | loss | perplexity

  float* sumx_g = (float*)d_ws;                                   // 128 KB
  float* cnorm  = (float*)((char*)d_ws + 131072);                 // 4 KB
  int*   hist   = (int*)((char*)d_ws + 135168);                   // 4 KB
  unsigned long long* pmin = (unsigned long long*)((char*)d_ws + 262144);  // 256 KB (poison-init OK)

  hipMemsetAsync(out + 2097152, 0, 8, stream);   // loss+perp accumulators
  hipMemsetAsync(hist, 0, 4096, stream);
  k_pre<<<264, 128, 0, stream>>>(x, cb, sumx_g, cnorm);
  k_dist<<<dim3(NPTS / PT, 2), 256, 0, stream>>>(x, cb, cnorm, sumx_g, pmin);
  k_fin<<<NPTS / 256, 256, 0, stream>>>(x, cb, pmin, hist, out);
  k_ot<<<1, 256, 0, stream>>>(hist, out);
}